// Round 2
// baseline (3218.919 us; speedup 1.0000x reference)
//
#include <hip/hip_runtime.h>
#include <math.h>

#define FD 128
#define NOUT 16
#define ALPHA_F 0.1f

// ---------- CSC build ----------

__global__ void count_kernel(const int* __restrict__ cols, int* __restrict__ cnt, int e) {
    int i = blockIdx.x * blockDim.x + threadIdx.x;
    if (i < e) atomicAdd(&cnt[cols[i]], 1);
}

__global__ void dinv_kernel(const int* __restrict__ cnt, float* __restrict__ dinv, int n) {
    int i = blockIdx.x * blockDim.x + threadIdx.x;
    if (i < n) {
        float deg = (float)(cnt[i] + 1);   // +1 self-loop
        dinv[i] = rsqrtf(deg);
    }
}

// single-block exclusive scan of (cnt[i]+1), off[n] = total nnz
__global__ void scan_kernel(const int* __restrict__ cnt, int* __restrict__ off, int n) {
    __shared__ int sh[1024];
    __shared__ int carry_s;
    if (threadIdx.x == 0) carry_s = 0;
    __syncthreads();
    for (int base = 0; base < n; base += 1024) {
        int i = base + (int)threadIdx.x;
        int v = (i < n) ? (cnt[i] + 1) : 0;
        sh[threadIdx.x] = v;
        __syncthreads();
        for (int d = 1; d < 1024; d <<= 1) {
            int t = (threadIdx.x >= (unsigned)d) ? sh[threadIdx.x - d] : 0;
            __syncthreads();
            sh[threadIdx.x] += t;
            __syncthreads();
        }
        int carry = carry_s;
        if (i < n) off[i] = carry + sh[threadIdx.x] - v;   // exclusive
        __syncthreads();
        if (threadIdx.x == 0) carry_s = carry + sh[1023];
        __syncthreads();
    }
    if (threadIdx.x == 0) off[n] = carry_s;
}

__global__ void fill_edges_kernel(const int* __restrict__ rows,
                                  const int* __restrict__ cols,
                                  const float* __restrict__ dinv,
                                  int* __restrict__ cur,
                                  int* __restrict__ src, float* __restrict__ wgt, int e) {
    int i = blockIdx.x * blockDim.x + threadIdx.x;
    if (i < e) {
        int r = rows[i];
        int c = cols[i];
        int pos = atomicAdd(&cur[c], 1);
        src[pos] = r;
        wgt[pos] = dinv[r] * dinv[c];
    }
}

__global__ void fill_loops_kernel(const float* __restrict__ dinv, int* __restrict__ cur,
                                  int* __restrict__ src, float* __restrict__ wgt, int n) {
    int i = blockIdx.x * blockDim.x + threadIdx.x;
    if (i < n) {
        int pos = atomicAdd(&cur[i], 1);
        src[pos] = i;
        wgt[pos] = dinv[i] * dinv[i];
    }
}

// ---------- compute kernels ----------

// Y[n,128] = X[n,128] @ W[128,128] + b ; 8 rows per 128-thread block
__global__ void gemm128_kernel(const float* __restrict__ X, const float* __restrict__ W,
                               const float* __restrict__ b, float* __restrict__ Y, int n) {
    const int TM = 8;
    __shared__ float xs[TM][FD];
    int r0 = blockIdx.x * TM;
    int f = threadIdx.x;
    #pragma unroll
    for (int r = 0; r < TM; ++r) {
        int ri = r0 + r;
        xs[r][f] = (ri < n) ? X[ri * FD + f] : 0.f;
    }
    __syncthreads();
    float acc[TM];
    #pragma unroll
    for (int r = 0; r < TM; ++r) acc[r] = 0.f;
    for (int k = 0; k < FD; ++k) {
        float wv = W[k * FD + f];
        #pragma unroll
        for (int r = 0; r < TM; ++r) acc[r] += xs[r][k] * wv;
    }
    float bb = b[f];
    #pragma unroll
    for (int r = 0; r < TM; ++r) {
        int ri = r0 + r;
        if (ri < n) Y[ri * FD + f] = acc[r] + bb;
    }
}

// one APPNP step: Xout = (1-a)*A_hat@Xin + a*X0, optional relu
__global__ void spmm_step_kernel(const int* __restrict__ off, const int* __restrict__ src,
                                 const float* __restrict__ wgt,
                                 const float* __restrict__ Xin, const float* __restrict__ X0,
                                 float* __restrict__ Xout, int n, int do_relu) {
    int i = blockIdx.x;
    if (i >= n) return;
    int f = threadIdx.x;
    int s = off[i], e = off[i + 1];
    float acc = 0.f;
    for (int p = s; p < e; ++p) {
        acc += wgt[p] * Xin[src[p] * FD + f];
    }
    float v = (1.0f - ALPHA_F) * acc + ALPHA_F * X0[i * FD + f];
    if (do_relu) v = fmaxf(v, 0.f);
    Xout[i * FD + f] = v;
}

// head: logits = H @ Wc + bc ; log_softmax per node. 16 lanes per node, 256 thr/block
__global__ void head_kernel(const float* __restrict__ H, const float* __restrict__ Wc,
                            const float* __restrict__ bc, float* __restrict__ out, int n) {
    int t = threadIdx.x;
    int o = t & (NOUT - 1);
    int node = blockIdx.x * (256 / NOUT) + (t >> 4);
    if (node >= n) return;
    float acc = bc[o];
    for (int k = 0; k < FD; ++k) {
        acc += H[node * FD + k] * Wc[k * NOUT + o];
    }
    float m = acc;
    #pragma unroll
    for (int d = NOUT / 2; d > 0; d >>= 1) m = fmaxf(m, __shfl_xor(m, d, NOUT));
    float ex = __expf(acc - m);
    float s = ex;
    #pragma unroll
    for (int d = NOUT / 2; d > 0; d >>= 1) s += __shfl_xor(s, d, NOUT);
    out[node * NOUT + o] = acc - m - __logf(s);
}

// ---------- launch ----------

static inline size_t align256(size_t x) { return (x + 255) & ~(size_t)255; }

extern "C" void kernel_launch(void* const* d_in, const int* in_sizes, int n_in,
                              void* d_out, int out_size, void* d_ws, size_t ws_size,
                              hipStream_t stream) {
    const float* x  = (const float*)d_in[0];
    const int*   ei = (const int*)d_in[1];          // int32 per harness contract
    const float* W1 = (const float*)d_in[2];
    const float* b1 = (const float*)d_in[3];
    const float* W2 = (const float*)d_in[4];
    const float* b2 = (const float*)d_in[5];
    const float* W3 = (const float*)d_in[6];
    const float* b3 = (const float*)d_in[7];
    const float* Wc = (const float*)d_in[8];
    const float* bc = (const float*)d_in[9];
    float* out = (float*)d_out;

    const int n = in_sizes[0] / FD;       // 50000
    const int e = in_sizes[1] / 2;        // 800000
    const int nnz = e + n;

    const int* rows = ei;
    const int* cols = ei + e;

    // workspace layout
    char* p = (char*)d_ws;
    int*   off  = (int*)p;            p += align256((size_t)(n + 1) * 4);
    int*   cur  = (int*)p;            p += align256((size_t)n * 4);
    float* dinv = (float*)p;          p += align256((size_t)n * 4);
    int*   srcb = (int*)p;            p += align256((size_t)nnz * 4);
    float* wgtb = (float*)p;          p += align256((size_t)nnz * 4);
    float* Z    = (float*)p;          p += align256((size_t)n * FD * 4);
    float* A    = (float*)p;          p += align256((size_t)n * FD * 4);
    float* B    = (float*)p;          p += align256((size_t)n * FD * 4);

    // ---- build CSC ----
    hipMemsetAsync(cur, 0, (size_t)n * 4, stream);
    count_kernel<<<(e + 255) / 256, 256, 0, stream>>>(cols, cur, e);
    dinv_kernel<<<(n + 255) / 256, 256, 0, stream>>>(cur, dinv, n);
    scan_kernel<<<1, 1024, 0, stream>>>(cur, off, n);
    hipMemcpyAsync(cur, off, (size_t)n * 4, hipMemcpyDeviceToDevice, stream);
    fill_edges_kernel<<<(e + 255) / 256, 256, 0, stream>>>(rows, cols, dinv, cur, srcb, wgtb, e);
    fill_loops_kernel<<<(n + 255) / 256, 256, 0, stream>>>(dinv, cur, srcb, wgtb, n);

    const int gemm_grid = (n + 7) / 8;

    const float* stage_in = x;
    const float* Wl[3] = { W1, W2, W3 };
    const float* bl[3] = { b1, b2, b3 };

    for (int st = 0; st < 3; ++st) {
        gemm128_kernel<<<gemm_grid, FD, 0, stream>>>(stage_in, Wl[st], bl[st], Z, n);
        const float* in = Z;
        float* o_ = A;
        for (int k = 0; k < 10; ++k) {
            int relu = (k == 9) ? 1 : 0;
            spmm_step_kernel<<<n, FD, 0, stream>>>(off, srcb, wgtb, in, Z, o_, n, relu);
            in = o_;
            o_ = (o_ == A) ? B : A;
        }
        stage_in = in;  // buffer holding step-10 (relu'd) result
    }

    head_kernel<<<(n + 15) / 16, 256, 0, stream>>>(stage_in, Wc, bc, out, n);
}

// Round 3
// 2745.211 us; speedup vs baseline: 1.1726x; 1.1726x over previous
//
#include <hip/hip_runtime.h>
#include <math.h>

#define FD 128
#define NOUT 16
#define ALPHA_F 0.1f

// ---------- bf16 helpers (bit-level, RNE) ----------
__device__ __forceinline__ float bflo(unsigned u) { return __uint_as_float(u << 16); }
__device__ __forceinline__ float bfhi(unsigned u) { return __uint_as_float(u & 0xffff0000u); }
__device__ __forceinline__ unsigned f2bf(float f) {
    unsigned u = __float_as_uint(f);
    u += 0x7fffu + ((u >> 16) & 1u);          // round-to-nearest-even
    return u >> 16;
}
__device__ __forceinline__ unsigned pack2(float a, float b) {
    return f2bf(a) | (f2bf(b) << 16);
}

// ---------- CSC build ----------

__global__ void count_kernel(const int* __restrict__ cols, int* __restrict__ cnt, int e) {
    int i = blockIdx.x * blockDim.x + threadIdx.x;
    if (i < e) atomicAdd(&cnt[cols[i]], 1);
}

__global__ void dinv_kernel(const int* __restrict__ cnt, float* __restrict__ dinv, int n) {
    int i = blockIdx.x * blockDim.x + threadIdx.x;
    if (i < n) dinv[i] = rsqrtf((float)(cnt[i] + 1));   // +1 self-loop
}

// three-kernel exclusive scan of (cnt[i]+1): partials -> base scan -> final
__global__ void scan_partial_kernel(const int* __restrict__ cnt, int* __restrict__ bsum, int n) {
    __shared__ int sh[256];
    int base = blockIdx.x * 1024 + threadIdx.x * 4;
    int s = 0;
    #pragma unroll
    for (int j = 0; j < 4; ++j) { int i = base + j; if (i < n) s += cnt[i] + 1; }
    sh[threadIdx.x] = s; __syncthreads();
    for (int d = 128; d > 0; d >>= 1) {
        if ((int)threadIdx.x < d) sh[threadIdx.x] += sh[threadIdx.x + d];
        __syncthreads();
    }
    if (threadIdx.x == 0) bsum[blockIdx.x] = sh[0];
}

__global__ void scan_base_kernel(int* __restrict__ bsum, int* __restrict__ off, int nb, int n) {
    if (threadIdx.x == 0 && blockIdx.x == 0) {
        int run = 0;
        for (int b = 0; b < nb; ++b) { int t = bsum[b]; bsum[b] = run; run += t; }
        off[n] = run;
    }
}

// writes off[i] and initializes cur[i]=off[i] (cursor for fill). cnt and cur may alias.
__global__ void scan_final_kernel(const int* __restrict__ cnt, const int* __restrict__ bsum,
                                  int* __restrict__ off, int* __restrict__ cur, int n) {
    __shared__ int sh[256];
    int t = threadIdx.x;
    int base_i = blockIdx.x * 1024 + t * 4;
    int v[4]; int s = 0;
    #pragma unroll
    for (int j = 0; j < 4; ++j) { int i = base_i + j; v[j] = (i < n) ? cnt[i] + 1 : 0; s += v[j]; }
    sh[t] = s; __syncthreads();
    for (int d = 1; d < 256; d <<= 1) {
        int x = (t >= d) ? sh[t - d] : 0;
        __syncthreads();
        sh[t] += x;
        __syncthreads();
    }
    int excl = sh[t] - s + bsum[blockIdx.x];
    #pragma unroll
    for (int j = 0; j < 4; ++j) {
        int i = base_i + j;
        if (i < n) { off[i] = excl; cur[i] = excl; }
        excl += v[j];
    }
}

__global__ void fill_edges_kernel(const int* __restrict__ rows, const int* __restrict__ cols,
                                  const float* __restrict__ dinv, int* __restrict__ cur,
                                  uint2* __restrict__ eg, int e) {
    int i = blockIdx.x * blockDim.x + threadIdx.x;
    if (i < e) {
        int r = rows[i];
        int c = cols[i];
        int pos = atomicAdd(&cur[c], 1);
        eg[pos] = make_uint2((unsigned)r, __float_as_uint(dinv[r] * dinv[c]));
    }
}

__global__ void fill_loops_kernel(const float* __restrict__ dinv, int* __restrict__ cur,
                                  uint2* __restrict__ eg, int n) {
    int i = blockIdx.x * blockDim.x + threadIdx.x;
    if (i < n) {
        int pos = atomicAdd(&cur[i], 1);
        eg[pos] = make_uint2((unsigned)i, __float_as_uint(dinv[i] * dinv[i]));
    }
}

// ---------- compute kernels ----------

// Y = X @ W + b ; writes Ab = bf16(Y) and Z0b = bf16(alpha*Y), packed 2 bf16/uint.
// 8 rows per 128-thread block. BF_IN selects fp32 or packed-bf16 input.
template <int BF_IN>
__global__ void gemm128_kernel(const void* __restrict__ Xv, const float* __restrict__ W,
                               const float* __restrict__ b,
                               unsigned* __restrict__ Ab, unsigned* __restrict__ Z0b, int n) {
    const int TM = 8;
    __shared__ float xs[TM][FD];
    int r0 = blockIdx.x * TM;
    int f = threadIdx.x;
    #pragma unroll
    for (int r = 0; r < TM; ++r) {
        int ri = r0 + r;
        float v = 0.f;
        if (ri < n) {
            if (BF_IN) {
                unsigned u = ((const unsigned*)Xv)[ri * 64 + (f >> 1)];
                v = (f & 1) ? bfhi(u) : bflo(u);
            } else {
                v = ((const float*)Xv)[ri * FD + f];
            }
        }
        xs[r][f] = v;
    }
    __syncthreads();
    float acc[TM];
    #pragma unroll
    for (int r = 0; r < TM; ++r) acc[r] = 0.f;
    for (int k = 0; k < FD; ++k) {
        float wv = W[k * FD + f];
        #pragma unroll
        for (int r = 0; r < TM; ++r) acc[r] += xs[r][k] * wv;
    }
    float bb = b[f];
    #pragma unroll
    for (int r = 0; r < TM; ++r) {
        int ri = r0 + r;
        float v = acc[r] + bb;
        float vo = __shfl_xor(v, 1);          // partner feature's value
        if (!(f & 1) && ri < n) {
            int idx = ri * 64 + (f >> 1);
            Ab[idx]  = pack2(v, vo);
            Z0b[idx] = pack2(ALPHA_F * v, ALPHA_F * vo);
        }
    }
}

// one APPNP step on packed-bf16 features: Xout = (1-a)*A_hat@Xin + (alpha*x0), fp32 accum.
// one wave (64 lanes) per destination node; 4 nodes per 256-thread block.
__global__ void spmm_bf16_kernel(const int* __restrict__ off, const uint2* __restrict__ eg,
                                 const unsigned* __restrict__ Xin, const unsigned* __restrict__ X0b,
                                 unsigned* __restrict__ Xout, int n, int relu) {
    int node = blockIdx.x * 4 + ((int)threadIdx.x >> 6);
    if (node >= n) return;
    int f2 = threadIdx.x & 63;
    int s = off[node], e = off[node + 1];
    float a0 = 0.f, a1 = 0.f;
    for (int p = s; p < e; ++p) {
        uint2 E = eg[p];
        float w = __uint_as_float(E.y);
        unsigned u = Xin[(size_t)E.x * 64 + f2];
        a0 += w * bflo(u);
        a1 += w * bfhi(u);
    }
    unsigned x0 = X0b[node * 64 + f2];
    float v0 = 0.9f * a0 + bflo(x0);
    float v1 = 0.9f * a1 + bfhi(x0);
    if (relu) { v0 = fmaxf(v0, 0.f); v1 = fmaxf(v1, 0.f); }
    Xout[node * 64 + f2] = pack2(v0, v1);
}

// head: logits = H @ Wc + bc ; log_softmax per node. 16 lanes/node, 256 thr/block.
__global__ void head_kernel(const unsigned* __restrict__ Hb, const float* __restrict__ Wc,
                            const float* __restrict__ bc, float* __restrict__ out, int n) {
    int t = threadIdx.x;
    int o = t & (NOUT - 1);
    int node = blockIdx.x * (256 / NOUT) + (t >> 4);
    if (node >= n) return;
    float acc = bc[o];
    const unsigned* hrow = Hb + node * 64;
    for (int k2 = 0; k2 < 64; ++k2) {
        unsigned u = hrow[k2];
        acc += bflo(u) * Wc[(2 * k2) * NOUT + o];
        acc += bfhi(u) * Wc[(2 * k2 + 1) * NOUT + o];
    }
    float m = acc;
    #pragma unroll
    for (int d = NOUT / 2; d > 0; d >>= 1) m = fmaxf(m, __shfl_xor(m, d, NOUT));
    float ex = __expf(acc - m);
    float s = ex;
    #pragma unroll
    for (int d = NOUT / 2; d > 0; d >>= 1) s += __shfl_xor(s, d, NOUT);
    out[node * NOUT + o] = acc - m - __logf(s);
}

// ---------- launch ----------

static inline size_t align256(size_t x) { return (x + 255) & ~(size_t)255; }

extern "C" void kernel_launch(void* const* d_in, const int* in_sizes, int n_in,
                              void* d_out, int out_size, void* d_ws, size_t ws_size,
                              hipStream_t stream) {
    const float* x  = (const float*)d_in[0];
    const int*   ei = (const int*)d_in[1];
    const float* W1 = (const float*)d_in[2];
    const float* b1 = (const float*)d_in[3];
    const float* W2 = (const float*)d_in[4];
    const float* b2 = (const float*)d_in[5];
    const float* W3 = (const float*)d_in[6];
    const float* b3 = (const float*)d_in[7];
    const float* Wc = (const float*)d_in[8];
    const float* bc = (const float*)d_in[9];
    float* out = (float*)d_out;

    const int n = in_sizes[0] / FD;       // 50000
    const int e = in_sizes[1] / 2;        // 800000
    const int nnz = e + n;
    const int nb = (n + 1023) / 1024;

    const int* rows = ei;
    const int* cols = ei + e;

    // workspace layout (~59 MB)
    char* p = (char*)d_ws;
    int*      off  = (int*)p;       p += align256((size_t)(n + 1) * 4);
    int*      cur  = (int*)p;       p += align256((size_t)n * 4);
    float*    dinv = (float*)p;     p += align256((size_t)n * 4);
    int*      bsum = (int*)p;       p += align256((size_t)nb * 4);
    uint2*    eg   = (uint2*)p;     p += align256((size_t)nnz * 8);
    unsigned* Ab   = (unsigned*)p;  p += align256((size_t)n * 64 * 4);
    unsigned* Bb   = (unsigned*)p;  p += align256((size_t)n * 64 * 4);
    unsigned* Z0b  = (unsigned*)p;  p += align256((size_t)n * 64 * 4);
    unsigned* Hb   = (unsigned*)p;  p += align256((size_t)n * 64 * 4);

    // ---- build CSC ----
    hipMemsetAsync(cur, 0, (size_t)n * 4, stream);
    count_kernel<<<(e + 255) / 256, 256, 0, stream>>>(cols, cur, e);
    dinv_kernel<<<(n + 255) / 256, 256, 0, stream>>>(cur, dinv, n);
    scan_partial_kernel<<<nb, 256, 0, stream>>>(cur, bsum, n);
    scan_base_kernel<<<1, 64, 0, stream>>>(bsum, off, nb, n);
    scan_final_kernel<<<nb, 256, 0, stream>>>(cur, bsum, off, cur, n);
    fill_edges_kernel<<<(e + 255) / 256, 256, 0, stream>>>(rows, cols, dinv, cur, eg, e);
    fill_loops_kernel<<<(n + 255) / 256, 256, 0, stream>>>(dinv, cur, eg, n);

    const int gemm_grid = (n + 7) / 8;
    const int spmm_grid = (n + 3) / 4;

    const float* Wl[3] = { W1, W2, W3 };
    const float* bl[3] = { b1, b2, b3 };
    const void* gin = x;

    for (int st = 0; st < 3; ++st) {
        if (st == 0)
            gemm128_kernel<0><<<gemm_grid, FD, 0, stream>>>(gin, Wl[st], bl[st], Ab, Z0b, n);
        else
            gemm128_kernel<1><<<gemm_grid, FD, 0, stream>>>(gin, Wl[st], bl[st], Ab, Z0b, n);
        unsigned* bufs[2] = { Ab, Bb };
        int cu = 0;
        for (int k = 0; k < 10; ++k) {
            unsigned* o_ = (k == 9) ? Hb : bufs[cu ^ 1];
            spmm_bf16_kernel<<<spmm_grid, 256, 0, stream>>>(off, eg, bufs[cu], Z0b, o_, n, k == 9);
            cu ^= 1;
        }
        gin = Hb;
    }

    head_kernel<<<(n + 15) / 16, 256, 0, stream>>>(Hb, Wc, bc, out, n);
}

// Round 4
// 1256.911 us; speedup vs baseline: 2.5610x; 2.1841x over previous
//
#include <hip/hip_runtime.h>
#include <math.h>

#define FD 128
#define NOUT 16
#define ALPHA_F 0.1f

// ---------- bf16 helpers (bit-level, RNE) ----------
__device__ __forceinline__ float bflo(unsigned u) { return __uint_as_float(u << 16); }
__device__ __forceinline__ float bfhi(unsigned u) { return __uint_as_float(u & 0xffff0000u); }
__device__ __forceinline__ unsigned f2bf(float f) {
    unsigned u = __float_as_uint(f);
    u += 0x7fffu + ((u >> 16) & 1u);          // round-to-nearest-even
    return u >> 16;
}
__device__ __forceinline__ unsigned pack2(float a, float b) {
    return f2bf(a) | (f2bf(b) << 16);
}

// ---------- CSC build ----------

__global__ void count_kernel(const int* __restrict__ cols, int* __restrict__ cnt, int e) {
    int i = blockIdx.x * blockDim.x + threadIdx.x;
    if (i < e) atomicAdd(&cnt[cols[i]], 1);
}

__global__ void dinv_kernel(const int* __restrict__ cnt, float* __restrict__ dinv, int n) {
    int i = blockIdx.x * blockDim.x + threadIdx.x;
    if (i < n) dinv[i] = rsqrtf((float)(cnt[i] + 1));   // +1 self-loop
}

// three-kernel exclusive scan of (cnt[i]+1): partials -> base scan -> final
__global__ void scan_partial_kernel(const int* __restrict__ cnt, int* __restrict__ bsum, int n) {
    __shared__ int sh[256];
    int base = blockIdx.x * 1024 + threadIdx.x * 4;
    int s = 0;
    #pragma unroll
    for (int j = 0; j < 4; ++j) { int i = base + j; if (i < n) s += cnt[i] + 1; }
    sh[threadIdx.x] = s; __syncthreads();
    for (int d = 128; d > 0; d >>= 1) {
        if ((int)threadIdx.x < d) sh[threadIdx.x] += sh[threadIdx.x + d];
        __syncthreads();
    }
    if (threadIdx.x == 0) bsum[blockIdx.x] = sh[0];
}

__global__ void scan_base_kernel(int* __restrict__ bsum, int* __restrict__ off, int nb, int n) {
    if (threadIdx.x == 0 && blockIdx.x == 0) {
        int run = 0;
        for (int b = 0; b < nb; ++b) { int t = bsum[b]; bsum[b] = run; run += t; }
        off[n] = run;
    }
}

// writes off[i] and initializes cur[i]=off[i] (cursor for fill). cnt and cur may alias.
__global__ void scan_final_kernel(const int* __restrict__ cnt, const int* __restrict__ bsum,
                                  int* __restrict__ off, int* __restrict__ cur, int n) {
    __shared__ int sh[256];
    int t = threadIdx.x;
    int base_i = blockIdx.x * 1024 + t * 4;
    int v[4]; int s = 0;
    #pragma unroll
    for (int j = 0; j < 4; ++j) { int i = base_i + j; v[j] = (i < n) ? cnt[i] + 1 : 0; s += v[j]; }
    sh[t] = s; __syncthreads();
    for (int d = 1; d < 256; d <<= 1) {
        int x = (t >= d) ? sh[t - d] : 0;
        __syncthreads();
        sh[t] += x;
        __syncthreads();
    }
    int excl = sh[t] - s + bsum[blockIdx.x];
    #pragma unroll
    for (int j = 0; j < 4; ++j) {
        int i = base_i + j;
        if (i < n) { off[i] = excl; cur[i] = excl; }
        excl += v[j];
    }
}

__global__ void fill_edges_kernel(const int* __restrict__ rows, const int* __restrict__ cols,
                                  const float* __restrict__ dinv, int* __restrict__ cur,
                                  uint2* __restrict__ eg, int e) {
    int i = blockIdx.x * blockDim.x + threadIdx.x;
    if (i < e) {
        int r = rows[i];
        int c = cols[i];
        int pos = atomicAdd(&cur[c], 1);
        eg[pos] = make_uint2((unsigned)r, __float_as_uint(dinv[r] * dinv[c]));
    }
}

__global__ void fill_loops_kernel(const float* __restrict__ dinv, int* __restrict__ cur,
                                  uint2* __restrict__ eg, int n) {
    int i = blockIdx.x * blockDim.x + threadIdx.x;
    if (i < n) {
        int pos = atomicAdd(&cur[i], 1);
        eg[pos] = make_uint2((unsigned)i, __float_as_uint(dinv[i] * dinv[i]));
    }
}

// ---------- compute kernels ----------

// Y = X @ W + b ; writes Ab = bf16(Y) and Z0b = bf16(alpha*Y), packed 2 bf16/uint.
// 8 rows per 128-thread block. BF_IN selects fp32 or packed-bf16 input.
template <int BF_IN>
__global__ void gemm128_kernel(const void* __restrict__ Xv, const float* __restrict__ W,
                               const float* __restrict__ b,
                               unsigned* __restrict__ Ab, unsigned* __restrict__ Z0b, int n) {
    const int TM = 8;
    __shared__ float xs[TM][FD];
    int r0 = blockIdx.x * TM;
    int f = threadIdx.x;
    #pragma unroll
    for (int r = 0; r < TM; ++r) {
        int ri = r0 + r;
        float v = 0.f;
        if (ri < n) {
            if (BF_IN) {
                unsigned u = ((const unsigned*)Xv)[ri * 64 + (f >> 1)];
                v = (f & 1) ? bfhi(u) : bflo(u);
            } else {
                v = ((const float*)Xv)[ri * FD + f];
            }
        }
        xs[r][f] = v;
    }
    __syncthreads();
    float acc[TM];
    #pragma unroll
    for (int r = 0; r < TM; ++r) acc[r] = 0.f;
    for (int k = 0; k < FD; ++k) {
        float wv = W[k * FD + f];
        #pragma unroll
        for (int r = 0; r < TM; ++r) acc[r] += xs[r][k] * wv;
    }
    float bb = b[f];
    #pragma unroll
    for (int r = 0; r < TM; ++r) {
        int ri = r0 + r;
        float v = acc[r] + bb;
        float vo = __shfl_xor(v, 1);          // partner feature's value
        if (!(f & 1) && ri < n) {
            int idx = ri * 64 + (f >> 1);
            Ab[idx]  = pack2(v, vo);
            Z0b[idx] = pack2(ALPHA_F * v, ALPHA_F * vo);
        }
    }
}

// one APPNP step on packed-bf16 features: Xout = (1-a)*A_hat@Xin + (alpha*x0), fp32 accum.
// one wave (64 lanes) per destination node; 4 nodes per 256-thread block.
// Edge loop unrolled x8 with all loads issued before use -> 8 outstanding gathers.
__global__ __launch_bounds__(256, 8)
void spmm_bf16_kernel(const int* __restrict__ off, const uint2* __restrict__ eg,
                      const unsigned* __restrict__ Xin, const unsigned* __restrict__ X0b,
                      unsigned* __restrict__ Xout, int n, int relu) {
    int node = blockIdx.x * 4 + ((int)threadIdx.x >> 6);
    if (node >= n) return;
    int f2 = threadIdx.x & 63;
    int s = off[node], e = off[node + 1];
    const unsigned* Xf = Xin + f2;
    unsigned x0 = X0b[node * 64 + f2];    // issued early, consumed at the end
    float a0 = 0.f, a1 = 0.f;
    int p = s;
    for (; p + 8 <= e; p += 8) {
        uint2 E0 = eg[p + 0], E1 = eg[p + 1], E2 = eg[p + 2], E3 = eg[p + 3];
        uint2 E4 = eg[p + 4], E5 = eg[p + 5], E6 = eg[p + 6], E7 = eg[p + 7];
        unsigned u0 = Xf[(size_t)E0.x * 64];
        unsigned u1 = Xf[(size_t)E1.x * 64];
        unsigned u2 = Xf[(size_t)E2.x * 64];
        unsigned u3 = Xf[(size_t)E3.x * 64];
        unsigned u4 = Xf[(size_t)E4.x * 64];
        unsigned u5 = Xf[(size_t)E5.x * 64];
        unsigned u6 = Xf[(size_t)E6.x * 64];
        unsigned u7 = Xf[(size_t)E7.x * 64];
        float w0 = __uint_as_float(E0.y), w1 = __uint_as_float(E1.y);
        float w2 = __uint_as_float(E2.y), w3 = __uint_as_float(E3.y);
        float w4 = __uint_as_float(E4.y), w5 = __uint_as_float(E5.y);
        float w6 = __uint_as_float(E6.y), w7 = __uint_as_float(E7.y);
        a0 += w0 * bflo(u0); a1 += w0 * bfhi(u0);
        a0 += w1 * bflo(u1); a1 += w1 * bfhi(u1);
        a0 += w2 * bflo(u2); a1 += w2 * bfhi(u2);
        a0 += w3 * bflo(u3); a1 += w3 * bfhi(u3);
        a0 += w4 * bflo(u4); a1 += w4 * bfhi(u4);
        a0 += w5 * bflo(u5); a1 += w5 * bfhi(u5);
        a0 += w6 * bflo(u6); a1 += w6 * bfhi(u6);
        a0 += w7 * bflo(u7); a1 += w7 * bfhi(u7);
    }
    for (; p + 2 <= e; p += 2) {
        uint2 E0 = eg[p], E1 = eg[p + 1];
        unsigned u0 = Xf[(size_t)E0.x * 64];
        unsigned u1 = Xf[(size_t)E1.x * 64];
        float w0 = __uint_as_float(E0.y), w1 = __uint_as_float(E1.y);
        a0 += w0 * bflo(u0); a1 += w0 * bfhi(u0);
        a0 += w1 * bflo(u1); a1 += w1 * bfhi(u1);
    }
    if (p < e) {
        uint2 E0 = eg[p];
        unsigned u0 = Xf[(size_t)E0.x * 64];
        float w0 = __uint_as_float(E0.y);
        a0 += w0 * bflo(u0); a1 += w0 * bfhi(u0);
    }
    float v0 = 0.9f * a0 + bflo(x0);
    float v1 = 0.9f * a1 + bfhi(x0);
    if (relu) { v0 = fmaxf(v0, 0.f); v1 = fmaxf(v1, 0.f); }
    Xout[node * 64 + f2] = pack2(v0, v1);
}

// head: logits = H @ Wc + bc ; log_softmax per node. 16 lanes/node, 256 thr/block.
__global__ void head_kernel(const unsigned* __restrict__ Hb, const float* __restrict__ Wc,
                            const float* __restrict__ bc, float* __restrict__ out, int n) {
    int t = threadIdx.x;
    int o = t & (NOUT - 1);
    int node = blockIdx.x * (256 / NOUT) + (t >> 4);
    if (node >= n) return;
    float acc = bc[o];
    const unsigned* hrow = Hb + node * 64;
    for (int k2 = 0; k2 < 64; ++k2) {
        unsigned u = hrow[k2];
        acc += bflo(u) * Wc[(2 * k2) * NOUT + o];
        acc += bfhi(u) * Wc[(2 * k2 + 1) * NOUT + o];
    }
    float m = acc;
    #pragma unroll
    for (int d = NOUT / 2; d > 0; d >>= 1) m = fmaxf(m, __shfl_xor(m, d, NOUT));
    float ex = __expf(acc - m);
    float s = ex;
    #pragma unroll
    for (int d = NOUT / 2; d > 0; d >>= 1) s += __shfl_xor(s, d, NOUT);
    out[node * NOUT + o] = acc - m - __logf(s);
}

// ---------- launch ----------

static inline size_t align256(size_t x) { return (x + 255) & ~(size_t)255; }

extern "C" void kernel_launch(void* const* d_in, const int* in_sizes, int n_in,
                              void* d_out, int out_size, void* d_ws, size_t ws_size,
                              hipStream_t stream) {
    const float* x  = (const float*)d_in[0];
    const int*   ei = (const int*)d_in[1];
    const float* W1 = (const float*)d_in[2];
    const float* b1 = (const float*)d_in[3];
    const float* W2 = (const float*)d_in[4];
    const float* b2 = (const float*)d_in[5];
    const float* W3 = (const float*)d_in[6];
    const float* b3 = (const float*)d_in[7];
    const float* Wc = (const float*)d_in[8];
    const float* bc = (const float*)d_in[9];
    float* out = (float*)d_out;

    const int n = in_sizes[0] / FD;       // 50000
    const int e = in_sizes[1] / 2;        // 800000
    const int nnz = e + n;
    const int nb = (n + 1023) / 1024;

    const int* rows = ei;
    const int* cols = ei + e;

    // workspace layout (~59 MB)
    char* p = (char*)d_ws;
    int*      off  = (int*)p;       p += align256((size_t)(n + 1) * 4);
    int*      cur  = (int*)p;       p += align256((size_t)n * 4);
    float*    dinv = (float*)p;     p += align256((size_t)n * 4);
    int*      bsum = (int*)p;       p += align256((size_t)nb * 4);
    uint2*    eg   = (uint2*)p;     p += align256((size_t)nnz * 8);
    unsigned* Ab   = (unsigned*)p;  p += align256((size_t)n * 64 * 4);
    unsigned* Bb   = (unsigned*)p;  p += align256((size_t)n * 64 * 4);
    unsigned* Z0b  = (unsigned*)p;  p += align256((size_t)n * 64 * 4);
    unsigned* Hb   = (unsigned*)p;  p += align256((size_t)n * 64 * 4);

    // ---- build CSC ----
    hipMemsetAsync(cur, 0, (size_t)n * 4, stream);
    count_kernel<<<(e + 255) / 256, 256, 0, stream>>>(cols, cur, e);
    dinv_kernel<<<(n + 255) / 256, 256, 0, stream>>>(cur, dinv, n);
    scan_partial_kernel<<<nb, 256, 0, stream>>>(cur, bsum, n);
    scan_base_kernel<<<1, 64, 0, stream>>>(bsum, off, nb, n);
    scan_final_kernel<<<nb, 256, 0, stream>>>(cur, bsum, off, cur, n);
    fill_edges_kernel<<<(e + 255) / 256, 256, 0, stream>>>(rows, cols, dinv, cur, eg, e);
    fill_loops_kernel<<<(n + 255) / 256, 256, 0, stream>>>(dinv, cur, eg, n);

    const int gemm_grid = (n + 7) / 8;
    const int spmm_grid = (n + 3) / 4;

    const float* Wl[3] = { W1, W2, W3 };
    const float* bl[3] = { b1, b2, b3 };
    const void* gin = x;

    for (int st = 0; st < 3; ++st) {
        if (st == 0)
            gemm128_kernel<0><<<gemm_grid, FD, 0, stream>>>(gin, Wl[st], bl[st], Ab, Z0b, n);
        else
            gemm128_kernel<1><<<gemm_grid, FD, 0, stream>>>(gin, Wl[st], bl[st], Ab, Z0b, n);
        unsigned* bufs[2] = { Ab, Bb };
        int cu = 0;
        for (int k = 0; k < 10; ++k) {
            unsigned* o_ = (k == 9) ? Hb : bufs[cu ^ 1];
            spmm_bf16_kernel<<<spmm_grid, 256, 0, stream>>>(off, eg, bufs[cu], Z0b, o_, n, k == 9);
            cu ^= 1;
        }
        gin = Hb;
    }

    head_kernel<<<(n + 15) / 16, 256, 0, stream>>>(Hb, Wc, bc, out, n);
}

// Round 5
// 1120.886 us; speedup vs baseline: 2.8718x; 1.1214x over previous
//
#include <hip/hip_runtime.h>
#include <math.h>

#define FD 128
#define NOUT 16
#define ALPHA_F 0.1f

typedef short short8 __attribute__((ext_vector_type(8)));
typedef float f32x4 __attribute__((ext_vector_type(4)));

// ---------- bf16 helpers (bit-level, RNE) ----------
__device__ __forceinline__ float bflo(unsigned u) { return __uint_as_float(u << 16); }
__device__ __forceinline__ float bfhi(unsigned u) { return __uint_as_float(u & 0xffff0000u); }
__device__ __forceinline__ unsigned f2bf(float f) {
    unsigned u = __float_as_uint(f);
    u += 0x7fffu + ((u >> 16) & 1u);          // round-to-nearest-even
    return u >> 16;
}
__device__ __forceinline__ unsigned pack2(float a, float b) {
    return f2bf(a) | (f2bf(b) << 16);
}

// ---------- CSC build ----------

__global__ void count_kernel(const int* __restrict__ cols, int* __restrict__ cnt, int e) {
    int i = blockIdx.x * blockDim.x + threadIdx.x;
    if (i < e) atomicAdd(&cnt[cols[i]], 1);
}

__global__ void dinv_kernel(const int* __restrict__ cnt, float* __restrict__ dinv, int n) {
    int i = blockIdx.x * blockDim.x + threadIdx.x;
    if (i < n) dinv[i] = rsqrtf((float)(cnt[i] + 1));   // +1 self-loop
}

// padded degree: true degree (cnt+1) rounded up to multiple of 8
__device__ __forceinline__ int padded(int cnt) { return (cnt + 8) & ~7; }

// three-kernel exclusive scan of padded degrees
__global__ void scan_partial_kernel(const int* __restrict__ cnt, int* __restrict__ bsum, int n) {
    __shared__ int sh[256];
    int base = blockIdx.x * 1024 + threadIdx.x * 4;
    int s = 0;
    #pragma unroll
    for (int j = 0; j < 4; ++j) { int i = base + j; if (i < n) s += padded(cnt[i]); }
    sh[threadIdx.x] = s; __syncthreads();
    for (int d = 128; d > 0; d >>= 1) {
        if ((int)threadIdx.x < d) sh[threadIdx.x] += sh[threadIdx.x + d];
        __syncthreads();
    }
    if (threadIdx.x == 0) bsum[blockIdx.x] = sh[0];
}

__global__ void scan_base_kernel(int* __restrict__ bsum, int* __restrict__ off, int nb, int n) {
    if (threadIdx.x == 0 && blockIdx.x == 0) {
        int run = 0;
        for (int b = 0; b < nb; ++b) { int t = bsum[b]; bsum[b] = run; run += t; }
        off[n] = run;
    }
}

// writes off[i] and cur[i]=off[i]. cnt and cur alias (read-before-write per thread).
__global__ void scan_final_kernel(const int* __restrict__ cnt, const int* __restrict__ bsum,
                                  int* __restrict__ off, int* __restrict__ cur, int n) {
    __shared__ int sh[256];
    int t = threadIdx.x;
    int base_i = blockIdx.x * 1024 + t * 4;
    int v[4]; int s = 0;
    #pragma unroll
    for (int j = 0; j < 4; ++j) { int i = base_i + j; v[j] = (i < n) ? padded(cnt[i]) : 0; s += v[j]; }
    sh[t] = s; __syncthreads();
    for (int d = 1; d < 256; d <<= 1) {
        int x = (t >= d) ? sh[t - d] : 0;
        __syncthreads();
        sh[t] += x;
        __syncthreads();
    }
    int excl = sh[t] - s + bsum[blockIdx.x];
    #pragma unroll
    for (int j = 0; j < 4; ++j) {
        int i = base_i + j;
        if (i < n) { off[i] = excl; cur[i] = excl; }
        excl += v[j];
    }
}

// edge record: low16 = src node id, high16 = bf16 weight
__global__ void fill_edges_kernel(const int* __restrict__ rows, const int* __restrict__ cols,
                                  const float* __restrict__ dinv, int* __restrict__ cur,
                                  unsigned* __restrict__ eg, int e) {
    int i = blockIdx.x * blockDim.x + threadIdx.x;
    if (i < e) {
        int r = rows[i];
        int c = cols[i];
        int pos = atomicAdd(&cur[c], 1);
        eg[pos] = (f2bf(dinv[r] * dinv[c]) << 16) | (unsigned)r;
    }
}

__global__ void fill_loops_kernel(const float* __restrict__ dinv, int* __restrict__ cur,
                                  unsigned* __restrict__ eg, int n) {
    int i = blockIdx.x * blockDim.x + threadIdx.x;
    if (i < n) {
        int pos = atomicAdd(&cur[i], 1);
        eg[pos] = (f2bf(dinv[i] * dinv[i]) << 16) | (unsigned)i;
    }
}

// ---------- pre-processing for MFMA GEMM ----------

// Wt[c][ku] = pack2(W[2ku][c], W[2ku+1][c]) : transposed, bf16-packed. 128x64 uints.
__global__ void wtrans_kernel(const float* __restrict__ W, unsigned* __restrict__ Wt) {
    int idx = blockIdx.x * 256 + threadIdx.x;
    if (idx < 128 * 64) {
        int c = idx >> 6, ku = idx & 63;
        Wt[idx] = pack2(W[(2 * ku) * FD + c], W[(2 * ku + 1) * FD + c]);
    }
}

// convert fp32 features -> packed bf16 (2 per uint)
__global__ void xconv_kernel(const float* __restrict__ x, unsigned* __restrict__ Xb, int total) {
    int idx = blockIdx.x * blockDim.x + threadIdx.x;
    if (idx < total) {
        float2 f = ((const float2*)x)[idx];
        Xb[idx] = pack2(f.x, f.y);
    }
}

// ---------- MFMA GEMM:  Y = X@W + b ; Ab = bf16(Y), Z0b = bf16(alpha*Y) ----------
// 256 thr = 4 waves; block covers 64 rows; wave w -> rows [blk*64+w*16, +16).
// K=128 in 4 steps of 32; N=128 as 8 tiles of 16. B^T (Wt) convention per m89/m92.
__global__ __launch_bounds__(256, 4)
void gemm_mfma_kernel(const unsigned* __restrict__ Xb, const unsigned* __restrict__ Wt,
                      const float* __restrict__ bias,
                      unsigned* __restrict__ Ab, unsigned* __restrict__ Z0b, int n) {
    int l = threadIdx.x & 63;
    int w = threadIdx.x >> 6;
    int l15 = l & 15, lq = l >> 4;
    int r0 = blockIdx.x * 64 + w * 16;
    int arow = min(r0 + l15, n - 1);
    const unsigned* aptr = Xb + (size_t)arow * 64 + lq * 4;
    const unsigned* bptr = Wt + (size_t)l15 * 64 + lq * 4;

    f32x4 acc[8];
    #pragma unroll
    for (int nt = 0; nt < 8; ++nt) acc[nt] = (f32x4){0.f, 0.f, 0.f, 0.f};

    #pragma unroll
    for (int kk = 0; kk < 4; ++kk) {
        short8 af = *(const short8*)(aptr + kk * 16);
        #pragma unroll
        for (int nt = 0; nt < 8; ++nt) {
            short8 bf = *(const short8*)(bptr + nt * 1024 + kk * 16);
            acc[nt] = __builtin_amdgcn_mfma_f32_16x16x32_bf16(af, bf, acc[nt], 0, 0, 0);
        }
    }

    #pragma unroll
    for (int nt = 0; nt < 8; ++nt) {
        float b_ = bias[nt * 16 + l15];
        #pragma unroll
        for (int j = 0; j < 4; ++j) {
            float v = acc[nt][j] + b_;
            float vp = __shfl_xor(v, 1);
            int row = r0 + lq * 4 + j;
            if (!(l & 1) && row < n) {
                int cu = nt * 8 + (l15 >> 1);
                Ab[(size_t)row * 64 + cu]  = pack2(v, vp);
                Z0b[(size_t)row * 64 + cu] = pack2(ALPHA_F * v, ALPHA_F * vp);
            }
        }
    }
}

// ---------- APPNP step: Xout = 0.9*A_hat@Xin + Z0b, fp32 accum ----------
// 2 nodes per wave (32 lanes each, uint2 = 4 bf16 features per lane).
// Padded degrees (mult of 8, zero-weight pads) -> aligned uint4 record loads.
__global__ __launch_bounds__(256, 8)
void spmm_bf16_kernel(const int* __restrict__ off, const unsigned* __restrict__ eg,
                      const unsigned* __restrict__ Xin, const unsigned* __restrict__ X0b,
                      unsigned* __restrict__ Xout, int n, int relu) {
    int node = blockIdx.x * 8 + ((int)threadIdx.x >> 5);
    if (node >= n) return;
    int lane31 = threadIdx.x & 31;
    int s = off[node];
    int degpad = off[node + 1] - s;               // multiple of 8, >= 8
    int dother = __shfl_xor(degpad, 32);          // other half's degpad
    int dm = max(degpad, dother);
    const uint2* Xg = (const uint2*)Xin;
    uint2 x0 = ((const uint2*)X0b)[node * 32 + lane31];   // issue early
    float a0 = 0.f, a1 = 0.f, a2 = 0.f, a3 = 0.f;

    for (int base = 0; base < dm; base += 8) {
        int p = s + min(base, degpad - 8);
        bool live = base < degpad;                // beyond-own-end chunks masked
        uint4 ra = *(const uint4*)(eg + p);
        uint4 rb = *(const uint4*)(eg + p + 4);
        uint2 g0 = Xg[(ra.x & 0xffffu) * 32 + lane31];
        uint2 g1 = Xg[(ra.y & 0xffffu) * 32 + lane31];
        uint2 g2 = Xg[(ra.z & 0xffffu) * 32 + lane31];
        uint2 g3 = Xg[(ra.w & 0xffffu) * 32 + lane31];
        uint2 g4 = Xg[(rb.x & 0xffffu) * 32 + lane31];
        uint2 g5 = Xg[(rb.y & 0xffffu) * 32 + lane31];
        uint2 g6 = Xg[(rb.z & 0xffffu) * 32 + lane31];
        uint2 g7 = Xg[(rb.w & 0xffffu) * 32 + lane31];
        float w0 = live ? bfhi(ra.x) : 0.f;
        float w1 = live ? bfhi(ra.y) : 0.f;
        float w2 = live ? bfhi(ra.z) : 0.f;
        float w3 = live ? bfhi(ra.w) : 0.f;
        float w4 = live ? bfhi(rb.x) : 0.f;
        float w5 = live ? bfhi(rb.y) : 0.f;
        float w6 = live ? bfhi(rb.z) : 0.f;
        float w7 = live ? bfhi(rb.w) : 0.f;
        a0 += w0 * bflo(g0.x); a1 += w0 * bfhi(g0.x); a2 += w0 * bflo(g0.y); a3 += w0 * bfhi(g0.y);
        a0 += w1 * bflo(g1.x); a1 += w1 * bfhi(g1.x); a2 += w1 * bflo(g1.y); a3 += w1 * bfhi(g1.y);
        a0 += w2 * bflo(g2.x); a1 += w2 * bfhi(g2.x); a2 += w2 * bflo(g2.y); a3 += w2 * bfhi(g2.y);
        a0 += w3 * bflo(g3.x); a1 += w3 * bfhi(g3.x); a2 += w3 * bflo(g3.y); a3 += w3 * bfhi(g3.y);
        a0 += w4 * bflo(g4.x); a1 += w4 * bfhi(g4.x); a2 += w4 * bflo(g4.y); a3 += w4 * bfhi(g4.y);
        a0 += w5 * bflo(g5.x); a1 += w5 * bfhi(g5.x); a2 += w5 * bflo(g5.y); a3 += w5 * bfhi(g5.y);
        a0 += w6 * bflo(g6.x); a1 += w6 * bfhi(g6.x); a2 += w6 * bflo(g6.y); a3 += w6 * bfhi(g6.y);
        a0 += w7 * bflo(g7.x); a1 += w7 * bfhi(g7.x); a2 += w7 * bflo(g7.y); a3 += w7 * bfhi(g7.y);
    }

    float v0 = 0.9f * a0 + bflo(x0.x);
    float v1 = 0.9f * a1 + bfhi(x0.x);
    float v2 = 0.9f * a2 + bflo(x0.y);
    float v3 = 0.9f * a3 + bfhi(x0.y);
    if (relu) {
        v0 = fmaxf(v0, 0.f); v1 = fmaxf(v1, 0.f);
        v2 = fmaxf(v2, 0.f); v3 = fmaxf(v3, 0.f);
    }
    ((uint2*)Xout)[node * 32 + lane31] = make_uint2(pack2(v0, v1), pack2(v2, v3));
}

// ---------- head: logits = H @ Wc + bc ; log_softmax. 16 lanes/node ----------
__global__ void head_kernel(const unsigned* __restrict__ Hb, const float* __restrict__ Wc,
                            const float* __restrict__ bc, float* __restrict__ out, int n) {
    int t = threadIdx.x;
    int o = t & (NOUT - 1);
    int node = blockIdx.x * (256 / NOUT) + (t >> 4);
    if (node >= n) return;
    float acc = bc[o];
    const uint4* hrow = (const uint4*)(Hb + (size_t)node * 64);
    #pragma unroll 4
    for (int k4 = 0; k4 < 16; ++k4) {
        uint4 u = hrow[k4];
        int k = k4 * 8;
        acc += bflo(u.x) * Wc[(k + 0) * NOUT + o];
        acc += bfhi(u.x) * Wc[(k + 1) * NOUT + o];
        acc += bflo(u.y) * Wc[(k + 2) * NOUT + o];
        acc += bfhi(u.y) * Wc[(k + 3) * NOUT + o];
        acc += bflo(u.z) * Wc[(k + 4) * NOUT + o];
        acc += bfhi(u.z) * Wc[(k + 5) * NOUT + o];
        acc += bflo(u.w) * Wc[(k + 6) * NOUT + o];
        acc += bfhi(u.w) * Wc[(k + 7) * NOUT + o];
    }
    float m = acc;
    #pragma unroll
    for (int d = NOUT / 2; d > 0; d >>= 1) m = fmaxf(m, __shfl_xor(m, d, NOUT));
    float ex = __expf(acc - m);
    float s = ex;
    #pragma unroll
    for (int d = NOUT / 2; d > 0; d >>= 1) s += __shfl_xor(s, d, NOUT);
    out[node * NOUT + o] = acc - m - __logf(s);
}

// ---------- launch ----------

static inline size_t align256(size_t x) { return (x + 255) & ~(size_t)255; }

extern "C" void kernel_launch(void* const* d_in, const int* in_sizes, int n_in,
                              void* d_out, int out_size, void* d_ws, size_t ws_size,
                              hipStream_t stream) {
    const float* x  = (const float*)d_in[0];
    const int*   ei = (const int*)d_in[1];
    const float* W1 = (const float*)d_in[2];
    const float* b1 = (const float*)d_in[3];
    const float* W2 = (const float*)d_in[4];
    const float* b2 = (const float*)d_in[5];
    const float* W3 = (const float*)d_in[6];
    const float* b3 = (const float*)d_in[7];
    const float* Wc = (const float*)d_in[8];
    const float* bc = (const float*)d_in[9];
    float* out = (float*)d_out;

    const int n = in_sizes[0] / FD;       // 50000
    const int e = in_sizes[1] / 2;        // 800000
    const int nnz_max = e + n + 8 * n + 16;   // padded upper bound
    const int nb = (n + 1023) / 1024;

    const int* rows = ei;
    const int* cols = ei + e;

    // workspace layout (~57 MB)
    char* p = (char*)d_ws;
    int*      off  = (int*)p;       p += align256((size_t)(n + 1) * 4);
    int*      cur  = (int*)p;       p += align256((size_t)n * 4);
    float*    dinv = (float*)p;     p += align256((size_t)n * 4);
    int*      bsum = (int*)p;       p += align256((size_t)nb * 4);
    unsigned* eg   = (unsigned*)p;  p += align256((size_t)nnz_max * 4);
    unsigned* Wt   = (unsigned*)p;  p += align256((size_t)3 * 8192 * 4);
    unsigned* Ab   = (unsigned*)p;  p += align256((size_t)n * 64 * 4);
    unsigned* Bb   = (unsigned*)p;  p += align256((size_t)n * 64 * 4);
    unsigned* Z0b  = (unsigned*)p;  p += align256((size_t)n * 64 * 4);
    unsigned* Hb   = (unsigned*)p;  p += align256((size_t)n * 64 * 4);

    // ---- build padded CSC ----
    hipMemsetAsync(cur, 0, (size_t)n * 4, stream);
    hipMemsetAsync(eg, 0, (size_t)nnz_max * 4, stream);
    count_kernel<<<(e + 255) / 256, 256, 0, stream>>>(cols, cur, e);
    dinv_kernel<<<(n + 255) / 256, 256, 0, stream>>>(cur, dinv, n);
    scan_partial_kernel<<<nb, 256, 0, stream>>>(cur, bsum, n);
    scan_base_kernel<<<1, 64, 0, stream>>>(bsum, off, nb, n);
    scan_final_kernel<<<nb, 256, 0, stream>>>(cur, bsum, off, cur, n);
    fill_edges_kernel<<<(e + 255) / 256, 256, 0, stream>>>(rows, cols, dinv, cur, eg, e);
    fill_loops_kernel<<<(n + 255) / 256, 256, 0, stream>>>(dinv, cur, eg, n);

    // ---- weight transpose + input convert ----
    wtrans_kernel<<<32, 256, 0, stream>>>(W1, Wt);
    wtrans_kernel<<<32, 256, 0, stream>>>(W2, Wt + 8192);
    wtrans_kernel<<<32, 256, 0, stream>>>(W3, Wt + 16384);
    xconv_kernel<<<(n * 64 + 255) / 256, 256, 0, stream>>>(x, Hb, n * 64);

    const int gemm_grid = (n + 63) / 64;
    const int spmm_grid = (n + 7) / 8;
    const float* bl[3] = { b1, b2, b3 };

    for (int st = 0; st < 3; ++st) {
        gemm_mfma_kernel<<<gemm_grid, 256, 0, stream>>>(Hb, Wt + st * 8192, bl[st], Ab, Z0b, n);
        unsigned* bufs[2] = { Ab, Bb };
        int cu = 0;
        for (int k = 0; k < 10; ++k) {
            unsigned* o_ = (k == 9) ? Hb : bufs[cu ^ 1];
            spmm_bf16_kernel<<<spmm_grid, 256, 0, stream>>>(off, eg, bufs[cu], Z0b, o_, n, k == 9);
            cu ^= 1;
        }
    }

    head_kernel<<<(n + 15) / 16, 256, 0, stream>>>(Hb, Wc, bc, out, n);
}